// Round 6
// baseline (18.575 us; speedup 1.0000x reference)
//
#include <hip/hip_runtime.h>
#include <hip/hip_bf16.h>

// ---------------------------------------------------------------------------
// HybridQuantumNet: 4-qubit default.qubit sim + Linear(2,2), B = 524288.
//
// out[b][o] = sum_{k in 3^4} C[k][o] * prod_q g_{k_q}(x_q), g = (1, cos, sin).
// C (162 floats, weights/fc-only) is computed per-block (redundantly) into
// LDS, then contracted per element with packed-FP32 math (v_pk_fma_f32):
// 4 sincos + 80 pk_fma per element. 512 blocks x 256 threads x 4 elem/thread.
// ---------------------------------------------------------------------------

#define NBLK 512
#define NTHR 256
#define EPT  4                       // elements per thread

typedef float f32x2 __attribute__((ext_vector_type(2)));

static __device__ __forceinline__ f32x2 pk_fma(f32x2 a, f32x2 b, f32x2 c) {
    f32x2 d;
    asm("v_pk_fma_f32 %0, %1, %2, %3" : "=v"(d) : "v"(a), "v"(b), "v"(c));
    return d;
}

__global__ __launch_bounds__(256) void qfused_kernel(
    const float4* __restrict__ x,    // [B] angle quads
    const float*  __restrict__ w,    // [2][4][3]
    const float*  __restrict__ fcw,  // [2][2]
    const float*  __restrict__ fcb,  // [2]
    float2*       __restrict__ out,  // [B]
    int B)
{
    __shared__ float rot[8][8];
    __shared__ float Ur[16][16], Ui[16][16];
    __shared__ float Mr[2][16][16], Mi[2][16][16];
    __shared__ alignas(16) float Cs[192];   // 3 segments of 54, 64-float apart

    const int t = threadIdx.x;
    const int stride = NBLK * NTHR;
    const int base = blockIdx.x * NTHR + t;

    // Issue the streaming x-loads up front; latency hides under prep.
    float4 xv[EPT];
#pragma unroll
    for (int e = 0; e < EPT; ++e) {
        int el = base + e * stride;
        if (el < B) xv[e] = x[el];
    }

    // ===================== per-block prep: weights -> Cs ===================
    // 1: Rot matrices. Rot = RZ(om) RY(th) RZ(phi).
    if (t < 8) {
        float phi = w[t*3+0], th = w[t*3+1], om = w[t*3+2];
        float ct, st, sp, cp, sm, cm;
        __sincosf(0.5f*th, &st, &ct);
        __sincosf(0.5f*(phi+om), &sp, &cp);
        __sincosf(0.5f*(phi-om), &sm, &cm);
        rot[t][0] =  cp*ct;  rot[t][1] = -sp*ct;
        rot[t][2] = -cm*st;  rot[t][3] = -sm*st;
        rot[t][4] =  cm*st;  rot[t][5] = -sm*st;
        rot[t][6] =  cp*ct;  rot[t][7] =  sp*ct;
    }
    __syncthreads();

    // 2: build U columns (wire q <-> bit (3-q))
    if (t < 16) {
        float re[16], im[16];
#pragma unroll
        for (int i = 0; i < 16; ++i) { re[i] = 0.0f; im[i] = 0.0f; }
        re[t] = 1.0f;
#pragma unroll
        for (int l = 0; l < 2; ++l) {
#pragma unroll
            for (int q = 0; q < 4; ++q) {
                const float* m = rot[l*4 + q];
                float m00r=m[0],m00i=m[1],m01r=m[2],m01i=m[3];
                float m10r=m[4],m10i=m[5],m11r=m[6],m11i=m[7];
                const int bit = 8 >> q;
#pragma unroll
                for (int i = 0; i < 16; ++i) {
                    if (i & bit) continue;
                    const int j = i | bit;
                    float a0r=re[i], a0i=im[i], a1r=re[j], a1i=im[j];
                    re[i] = m00r*a0r - m00i*a0i + m01r*a1r - m01i*a1i;
                    im[i] = m00r*a0i + m00i*a0r + m01r*a1i + m01i*a1r;
                    re[j] = m10r*a0r - m10i*a0i + m11r*a1r - m11i*a1i;
                    im[j] = m10r*a0i + m10i*a0r + m11r*a1i + m11i*a1r;
                }
            }
            const int r = (l % 3) + 1;
#pragma unroll
            for (int q = 0; q < 4; ++q) {
                const int cbit = 8 >> q;
                const int tbit = 8 >> ((q + r) & 3);
#pragma unroll
                for (int i = 0; i < 16; ++i) {
                    if ((i & cbit) && !(i & tbit)) {
                        const int j = i | tbit;
                        float tr = re[i]; re[i] = re[j]; re[j] = tr;
                        float ti = im[i]; im[i] = im[j]; im[j] = ti;
                    }
                }
            }
        }
#pragma unroll
        for (int k = 0; k < 16; ++k) { Ur[k][t] = re[k]; Ui[k][t] = im[k]; }
    }
    __syncthreads();

    // 3: M_o = U^dag Z_o U  (o=0: sign bit8, o=1: sign bit4)
    {
        const int i = t >> 4, j = t & 15;
        float r0=0, i0=0, r1=0, i1=0;
#pragma unroll
        for (int k = 0; k < 16; ++k) {
            float ar = Ur[k][i], ai = Ui[k][i];
            float br = Ur[k][j], bi = Ui[k][j];
            float pr = ar*br + ai*bi;
            float pi = ar*bi - ai*br;
            float sg0 = (k & 8) ? -1.0f : 1.0f;
            float sg1 = (k & 4) ? -1.0f : 1.0f;
            r0 += sg0*pr; i0 += sg0*pi;
            r1 += sg1*pr; i1 += sg1*pi;
        }
        Mr[0][i][j] = r0; Mi[0][i][j] = i0;
        Mr[1][i][j] = r1; Mi[1][i][j] = i1;
    }
    __syncthreads();

    // 4: project onto per-qubit {1, cos, sin} basis, fold fc, write Cs.
    // Layout: Cs[k0*64 + (k1*9+k2*3+k3)*2 + o]
    if (t < 81) {
        const int k3 = t % 3, k2 = (t/3) % 3, k1 = (t/9) % 3, k0 = t / 27;
        const int kd[4] = {k0, k1, k2, k3};
        int mask2 = 0, mask1 = 0;
#pragma unroll
        for (int q = 0; q < 4; ++q) {
            const int bit = 8 >> q;
            if (kd[q] == 2) mask2 |= bit;
            else if (kd[q] == 1) mask1 |= bit;
        }
        float z[2];
#pragma unroll
        for (int o = 0; o < 2; ++o) {
            float cr = 0.0f;
            for (int i = 0; i < 16; ++i) {
                const int j = i ^ mask2;
                const float mr = Mr[o][i][j], mi = Mi[o][i][j];
                const int s1 = __popc(mask1 & i) & 1;
                const int a  = __popc(mask2 & i);
                const int bb = __popc(mask2) - a;
                const int ip = ((a - bb) % 4 + 4) & 3;
                float wr, wi;
                switch (ip) {
                    case 0:  wr =  1.0f; wi =  0.0f; break;
                    case 1:  wr =  0.0f; wi =  1.0f; break;
                    case 2:  wr = -1.0f; wi =  0.0f; break;
                    default: wr =  0.0f; wi = -1.0f; break;
                }
                if (s1) { wr = -wr; wi = -wi; }
                cr += wr*mr - wi*mi;
            }
            z[o] = cr * 0.0625f;
        }
        const int rest = (t % 27) * 2;
#pragma unroll
        for (int o = 0; o < 2; ++o) {
            float v = z[0]*fcw[o*2+0] + z[1]*fcw[o*2+1];
            if (t == 0) v += fcb[o];
            Cs[k0*64 + rest + o] = v;
        }
    }
    __syncthreads();

    // =============== main: packed-FP32 contraction per element =============
    const f32x2* Cv = (const f32x2*)Cs;   // segments at pair-index 0, 32, 64
#pragma unroll
    for (int e = 0; e < EPT; ++e) {
        float cc[4], ss[4];
        __sincosf(xv[e].x, &ss[0], &cc[0]);
        __sincosf(xv[e].y, &ss[1], &cc[1]);
        __sincosf(xv[e].z, &ss[2], &cc[2]);
        __sincosf(xv[e].w, &ss[3], &cc[3]);
        const f32x2 c0p = {cc[0], cc[0]}, s0p = {ss[0], ss[0]};
        const f32x2 c1p = {cc[1], cc[1]}, s1p = {ss[1], ss[1]};
        const f32x2 c2p = {cc[2], cc[2]}, s2p = {ss[2], ss[2]};
        const f32x2 c3p = {cc[3], cc[3]}, s3p = {ss[3], ss[3]};

        f32x2 a2v[27];
#pragma unroll
        for (int k = 0; k < 27; ++k)
            a2v[k] = pk_fma(c0p, Cv[32 + k], pk_fma(s0p, Cv[64 + k], Cv[k]));

        f32x2 a3v[9];
#pragma unroll
        for (int n = 0; n < 9; ++n)
            a3v[n] = pk_fma(c1p, a2v[9 + n], pk_fma(s1p, a2v[18 + n], a2v[n]));

        f32x2 a4v[3];
#pragma unroll
        for (int p = 0; p < 3; ++p)
            a4v[p] = pk_fma(c2p, a3v[3 + p], pk_fma(s2p, a3v[6 + p], a3v[p]));

        f32x2 ov = pk_fma(c3p, a4v[1], pk_fma(s3p, a4v[2], a4v[0]));

        const int el = base + e * stride;
        if (el < B) {
            float2 o; o.x = ov.x; o.y = ov.y;
            out[el] = o;
        }
    }
}

extern "C" void kernel_launch(void* const* d_in, const int* in_sizes, int n_in,
                              void* d_out, int out_size, void* d_ws, size_t ws_size,
                              hipStream_t stream) {
    const float* x   = (const float*)d_in[0];   // [B,4]
    const float* w   = (const float*)d_in[1];   // [2,4,3]
    const float* fcw = (const float*)d_in[2];   // [2,2]
    const float* fcb = (const float*)d_in[3];   // [2]
    float* out = (float*)d_out;                 // [B,2]

    const int B = in_sizes[0] / 4;

    qfused_kernel<<<NBLK, NTHR, 0, stream>>>(
        (const float4*)x, w, fcw, fcb, (float2*)out, B);
}

// Round 7
// 17.091 us; speedup vs baseline: 1.0869x; 1.0869x over previous
//
#include <hip/hip_runtime.h>
#include <hip/hip_bf16.h>

// ---------------------------------------------------------------------------
// HybridQuantumNet: 4-qubit default.qubit sim + Linear(2,2), B = 524288.
//
// out[b][o] = sum_{k in 3^4} C[k][o] * prod_q g_{k_q}(x_q), g = (1, cos, sin).
// C (162 floats, weights/fc-only) is computed per-block (redundantly) into
// LDS, then contracted with packed-FP32 (v_pk_fma_f32), TWO elements
// interleaved for ILP (R5 structure + R6 packed math).
// 512 blocks x 256 threads x 4 elements/thread.
// ---------------------------------------------------------------------------

#define NBLK 512
#define NTHR 256
#define EPT  4                       // elements per thread

typedef float f32x2 __attribute__((ext_vector_type(2)));

static __device__ __forceinline__ f32x2 pk_fma(f32x2 a, f32x2 b, f32x2 c) {
    f32x2 d;
    asm("v_pk_fma_f32 %0, %1, %2, %3" : "=v"(d) : "v"(a), "v"(b), "v"(c));
    return d;
}

__global__ __launch_bounds__(256) void qfused_kernel(
    const float4* __restrict__ x,    // [B] angle quads
    const float*  __restrict__ w,    // [2][4][3]
    const float*  __restrict__ fcw,  // [2][2]
    const float*  __restrict__ fcb,  // [2]
    float2*       __restrict__ out,  // [B]
    int B)
{
    __shared__ float rot[8][8];
    __shared__ float Ur[16][16], Ui[16][16];
    __shared__ float Mr[2][16][16], Mi[2][16][16];
    __shared__ alignas(16) float Cs[192];   // 3 segments of 54, 64-float apart

    const int t = threadIdx.x;
    const int stride = NBLK * NTHR;
    const int base = blockIdx.x * NTHR + t;

    // Issue the streaming x-loads up front; latency hides under prep.
    float4 xv[EPT];
#pragma unroll
    for (int e = 0; e < EPT; ++e) {
        int el = base + e * stride;
        if (el < B) xv[e] = x[el];
    }

    // ===================== per-block prep: weights -> Cs ===================
    // 1: Rot matrices. Rot = RZ(om) RY(th) RZ(phi).
    if (t < 8) {
        float phi = w[t*3+0], th = w[t*3+1], om = w[t*3+2];
        float ct, st, sp, cp, sm, cm;
        __sincosf(0.5f*th, &st, &ct);
        __sincosf(0.5f*(phi+om), &sp, &cp);
        __sincosf(0.5f*(phi-om), &sm, &cm);
        rot[t][0] =  cp*ct;  rot[t][1] = -sp*ct;
        rot[t][2] = -cm*st;  rot[t][3] = -sm*st;
        rot[t][4] =  cm*st;  rot[t][5] = -sm*st;
        rot[t][6] =  cp*ct;  rot[t][7] =  sp*ct;
    }
    __syncthreads();

    // 2: build U columns (wire q <-> bit (3-q))
    if (t < 16) {
        float re[16], im[16];
#pragma unroll
        for (int i = 0; i < 16; ++i) { re[i] = 0.0f; im[i] = 0.0f; }
        re[t] = 1.0f;
#pragma unroll
        for (int l = 0; l < 2; ++l) {
#pragma unroll
            for (int q = 0; q < 4; ++q) {
                const float* m = rot[l*4 + q];
                float m00r=m[0],m00i=m[1],m01r=m[2],m01i=m[3];
                float m10r=m[4],m10i=m[5],m11r=m[6],m11i=m[7];
                const int bit = 8 >> q;
#pragma unroll
                for (int i = 0; i < 16; ++i) {
                    if (i & bit) continue;
                    const int j = i | bit;
                    float a0r=re[i], a0i=im[i], a1r=re[j], a1i=im[j];
                    re[i] = m00r*a0r - m00i*a0i + m01r*a1r - m01i*a1i;
                    im[i] = m00r*a0i + m00i*a0r + m01r*a1i + m01i*a1r;
                    re[j] = m10r*a0r - m10i*a0i + m11r*a1r - m11i*a1i;
                    im[j] = m10r*a0i + m10i*a0r + m11r*a1i + m11i*a1r;
                }
            }
            const int r = (l % 3) + 1;
#pragma unroll
            for (int q = 0; q < 4; ++q) {
                const int cbit = 8 >> q;
                const int tbit = 8 >> ((q + r) & 3);
#pragma unroll
                for (int i = 0; i < 16; ++i) {
                    if ((i & cbit) && !(i & tbit)) {
                        const int j = i | tbit;
                        float tr = re[i]; re[i] = re[j]; re[j] = tr;
                        float ti = im[i]; im[i] = im[j]; im[j] = ti;
                    }
                }
            }
        }
#pragma unroll
        for (int k = 0; k < 16; ++k) { Ur[k][t] = re[k]; Ui[k][t] = im[k]; }
    }
    __syncthreads();

    // 3: M_o = U^dag Z_o U  (o=0: sign bit8, o=1: sign bit4)
    {
        const int i = t >> 4, j = t & 15;
        float r0=0, i0=0, r1=0, i1=0;
#pragma unroll
        for (int k = 0; k < 16; ++k) {
            float ar = Ur[k][i], ai = Ui[k][i];
            float br = Ur[k][j], bi = Ui[k][j];
            float pr = ar*br + ai*bi;
            float pi = ar*bi - ai*br;
            float sg0 = (k & 8) ? -1.0f : 1.0f;
            float sg1 = (k & 4) ? -1.0f : 1.0f;
            r0 += sg0*pr; i0 += sg0*pi;
            r1 += sg1*pr; i1 += sg1*pi;
        }
        Mr[0][i][j] = r0; Mi[0][i][j] = i0;
        Mr[1][i][j] = r1; Mi[1][i][j] = i1;
    }
    __syncthreads();

    // 4: project onto per-qubit {1, cos, sin} basis, fold fc, write Cs.
    // Layout: Cs[k0*64 + (k1*9+k2*3+k3)*2 + o]
    if (t < 81) {
        const int k3 = t % 3, k2 = (t/3) % 3, k1 = (t/9) % 3, k0 = t / 27;
        const int kd[4] = {k0, k1, k2, k3};
        int mask2 = 0, mask1 = 0;
#pragma unroll
        for (int q = 0; q < 4; ++q) {
            const int bit = 8 >> q;
            if (kd[q] == 2) mask2 |= bit;
            else if (kd[q] == 1) mask1 |= bit;
        }
        float z[2];
#pragma unroll
        for (int o = 0; o < 2; ++o) {
            float cr = 0.0f;
            for (int i = 0; i < 16; ++i) {
                const int j = i ^ mask2;
                const float mr = Mr[o][i][j], mi = Mi[o][i][j];
                const int s1 = __popc(mask1 & i) & 1;
                const int a  = __popc(mask2 & i);
                const int bb = __popc(mask2) - a;
                const int ip = ((a - bb) % 4 + 4) & 3;
                float wr, wi;
                switch (ip) {
                    case 0:  wr =  1.0f; wi =  0.0f; break;
                    case 1:  wr =  0.0f; wi =  1.0f; break;
                    case 2:  wr = -1.0f; wi =  0.0f; break;
                    default: wr =  0.0f; wi = -1.0f; break;
                }
                if (s1) { wr = -wr; wi = -wi; }
                cr += wr*mr - wi*mi;
            }
            z[o] = cr * 0.0625f;
        }
        const int rest = (t % 27) * 2;
#pragma unroll
        for (int o = 0; o < 2; ++o) {
            float v = z[0]*fcw[o*2+0] + z[1]*fcw[o*2+1];
            if (t == 0) v += fcb[o];
            Cs[k0*64 + rest + o] = v;
        }
    }
    __syncthreads();

    // ========= main: packed-FP32, two elements interleaved (ILP=2) =========
    const f32x2* Cv = (const f32x2*)Cs;   // segments at pair-index 0, 32, 64
#pragma unroll
    for (int pp = 0; pp < EPT / 2; ++pp) {
        const int eA = 2*pp, eB = 2*pp + 1;
        float cA[4], sA[4], cB[4], sB[4];
        __sincosf(xv[eA].x, &sA[0], &cA[0]);
        __sincosf(xv[eA].y, &sA[1], &cA[1]);
        __sincosf(xv[eA].z, &sA[2], &cA[2]);
        __sincosf(xv[eA].w, &sA[3], &cA[3]);
        __sincosf(xv[eB].x, &sB[0], &cB[0]);
        __sincosf(xv[eB].y, &sB[1], &cB[1]);
        __sincosf(xv[eB].z, &sB[2], &cB[2]);
        __sincosf(xv[eB].w, &sB[3], &cB[3]);

        const f32x2 c0A = {cA[0], cA[0]}, s0A = {sA[0], sA[0]};
        const f32x2 c1A = {cA[1], cA[1]}, s1A = {sA[1], sA[1]};
        const f32x2 c2A = {cA[2], cA[2]}, s2A = {sA[2], sA[2]};
        const f32x2 c3A = {cA[3], cA[3]}, s3A = {sA[3], sA[3]};
        const f32x2 c0B = {cB[0], cB[0]}, s0B = {sB[0], sB[0]};
        const f32x2 c1B = {cB[1], cB[1]}, s1B = {sB[1], sB[1]};
        const f32x2 c2B = {cB[2], cB[2]}, s2B = {sB[2], sB[2]};
        const f32x2 c3B = {cB[3], cB[3]}, s3B = {sB[3], sB[3]};

        f32x2 a2A[27], a2B[27];
#pragma unroll
        for (int k = 0; k < 27; ++k) {
            const f32x2 q0 = Cv[k], q1 = Cv[32 + k], q2 = Cv[64 + k];
            a2A[k] = pk_fma(c0A, q1, pk_fma(s0A, q2, q0));
            a2B[k] = pk_fma(c0B, q1, pk_fma(s0B, q2, q0));
        }

        f32x2 a3A[9], a3B[9];
#pragma unroll
        for (int n = 0; n < 9; ++n) {
            a3A[n] = pk_fma(c1A, a2A[9 + n], pk_fma(s1A, a2A[18 + n], a2A[n]));
            a3B[n] = pk_fma(c1B, a2B[9 + n], pk_fma(s1B, a2B[18 + n], a2B[n]));
        }

        f32x2 a4A[3], a4B[3];
#pragma unroll
        for (int p = 0; p < 3; ++p) {
            a4A[p] = pk_fma(c2A, a3A[3 + p], pk_fma(s2A, a3A[6 + p], a3A[p]));
            a4B[p] = pk_fma(c2B, a3B[3 + p], pk_fma(s2B, a3B[6 + p], a3B[p]));
        }

        f32x2 oA = pk_fma(c3A, a4A[1], pk_fma(s3A, a4A[2], a4A[0]));
        f32x2 oB = pk_fma(c3B, a4B[1], pk_fma(s3B, a4B[2], a4B[0]));

        const int elA = base + eA * stride;
        const int elB = base + eB * stride;
        if (elA < B) { float2 o; o.x = oA.x; o.y = oA.y; out[elA] = o; }
        if (elB < B) { float2 o; o.x = oB.x; o.y = oB.y; out[elB] = o; }
    }
}

extern "C" void kernel_launch(void* const* d_in, const int* in_sizes, int n_in,
                              void* d_out, int out_size, void* d_ws, size_t ws_size,
                              hipStream_t stream) {
    const float* x   = (const float*)d_in[0];   // [B,4]
    const float* w   = (const float*)d_in[1];   // [2,4,3]
    const float* fcw = (const float*)d_in[2];   // [2,2]
    const float* fcb = (const float*)d_in[3];   // [2]
    float* out = (float*)d_out;                 // [B,2]

    const int B = in_sizes[0] / 4;

    qfused_kernel<<<NBLK, NTHR, 0, stream>>>(
        (const float4*)x, w, fcw, fcb, (float2*)out, B);
}